// Round 18
// baseline (197.795 us; speedup 1.0000x reference)
//
#include <hip/hip_runtime.h>
#include <hip/hip_bf16.h>
#include <stdint.h>

// Problem constants (f32 I/O; bf16 internal compute)
constexpr int Hh = 16, Ll = 1024, Dd = 1024, DHh = 64, CL = 1024, TKV = 2048;
constexpr size_t OUT_ELEMS = 4ull * 1024 * 1024;   // B*L*D = 4,194,304 floats
constexpr float LOG2E = 1.44269504088896340736f;

typedef __attribute__((ext_vector_type(8))) short short8;
typedef __attribute__((ext_vector_type(4))) float floatx4;

#define MFMA16(a, b, c) __builtin_amdgcn_mfma_f32_16x16x32_bf16(a, b, c, 0, 0, 0)

// native 2^x (v_exp_f32); libm exp2f carries ~6 VALU ops of range handling.
__device__ __forceinline__ float fexp2(float x) {
#if __has_builtin(__builtin_amdgcn_exp2f)
    return __builtin_amdgcn_exp2f(x);
#else
    float r;
    asm("v_exp_f32 %0, %1" : "=v"(r) : "v"(x));
    return r;
#endif
}

__device__ __forceinline__ short bfs(float x) {
    union { __hip_bfloat16 h; short s; } u;
    u.h = __float2bfloat16(x);
    return u.s;
}

__device__ __forceinline__ short8 cvt8(const float* p) {
    float4 a = *(const float4*)p;
    float4 b = *(const float4*)(p + 4);
    short8 r;
    r[0] = bfs(a.x); r[1] = bfs(a.y); r[2] = bfs(a.z); r[3] = bfs(a.w);
    r[4] = bfs(b.x); r[5] = bfs(b.y); r[6] = bfs(b.z); r[7] = bfs(b.w);
    return r;
}

__device__ __forceinline__ void gload_lds16(const __hip_bfloat16* g, __hip_bfloat16* l) {
    __builtin_amdgcn_global_load_lds((const __attribute__((address_space(1))) void*)g,
                                     (__attribute__((address_space(3))) void*)l, 16, 0, 0);
}

// V^T side-buffer swizzle: element (t,d) -> vbf[((bh*16 + t/128)*64 + d)*128 + ((t&127) ^ (sw(d)<<3))]
__device__ __forceinline__ int vswz(int d) { return ((d >> 3) ^ d) & 7; }

// ---------------------------------------------------------------------------
// Prep: 4 weight matrices (1024x1024 f32) -> bf16 ws, CHUNK-SWIZZLED layout:
// within each row's 64-col block, 8-elem chunk cw stored at cw ^ (row&7).
// ---------------------------------------------------------------------------
__global__ __launch_bounds__(256) void convert_w_kernel(
    const float* __restrict__ Wq, const float* __restrict__ Wk,
    const float* __restrict__ Wv, const float* __restrict__ Wo,
    __hip_bfloat16* __restrict__ Wb) {
    int c = blockIdx.x * 256 + threadIdx.x;   // 524,288 chunks of 8
    int wsel = c >> 17;
    int within = c & 131071;                  // chunk within matrix
    int row = within >> 7;                    // 128 chunks per row
    int cir = within & 127;                   // chunk in row
    int kb = cir >> 3, cw = cir & 7;
    int swc = cw ^ (row & 7);
    const float* src = (wsel == 0) ? Wq : (wsel == 1) ? Wk : (wsel == 2) ? Wv : Wo;
    *(short8*)(Wb + ((size_t)wsel << 20) + ((size_t)row << 10) + (kb << 6) + (swc << 3)) =
        cvt8(src + (size_t)within * 8);
}

// ---------------------------------------------------------------------------
// Fused QKV projection GEMM + cache copy: grid (64,8,4). ROUND-16 CONFIG.
// z=0: cache copy (memory-bound; dispatched FIRST to overlap GEMM blocks).
// z=1: bf16 Q ws (B,H,L,DH) scaled 0.125*log2e.
// z=2: f32 new_cache K half + bf16 swizzled kbf.
// z=3: f32 new_cache V half + bf16 swizzled vbf.
// LDS tiles chunk-swizzled (T2): reads XOR chunk with row&7 -> 0 conflicts.
// ---------------------------------------------------------------------------
__global__ __launch_bounds__(256) void gemm_qkv(
    const float* __restrict__ Aq, const float* __restrict__ Ak,
    const float* __restrict__ Av, const float* __restrict__ cache,
    const __hip_bfloat16* __restrict__ Wb,
    const float* __restrict__ bq, const float* __restrict__ bk,
    const float* __restrict__ bv, __hip_bfloat16* __restrict__ qws,
    float* __restrict__ outc, __hip_bfloat16* __restrict__ kbf,
    __hip_bfloat16* __restrict__ vbf) {
    constexpr int K = 1024, BK = 64;
    __shared__ alignas(16) __hip_bfloat16 As[64 * BK];    //  8 KB
    __shared__ alignas(16) __hip_bfloat16 Bs[128 * BK];   // 16 KB

    if (blockIdx.z == 0) {
        // ---- cache copy slice: 512 blocks x 2048 chunks of 8 floats ----
        int id = blockIdx.y * 64 + blockIdx.x;
#pragma unroll
        for (int it = 0; it < 8; it++) {
            int c = id * 2048 + it * 256 + threadIdx.x;   // [0, 1048576)
            int bh  = c >> 14;
            int rem = c & 16383;
            int t = rem >> 4, part = rem & 15;            // 0-7: K, 8-15: V
            const float* s = cache + (size_t)c * 8;
            float* d = outc + OUT_ELEMS + (size_t)bh * 262144 + (size_t)rem * 8;
            *(float4*)d       = *(const float4*)s;
            *(float4*)(d + 4) = *(const float4*)(s + 4);
            short8 bv8 = cvt8(s);
            if (part < 8) {
                *(short8*)&kbf[(size_t)bh * 131072 + (size_t)t * 64 +
                               ((part ^ (t & 7)) << 3)] = bv8;
            } else {
                int d0 = (part - 8) * 8;
#pragma unroll
                for (int e = 0; e < 8; e++) {
                    int dd = d0 + e;
                    ((short*)vbf)[((size_t)(bh * 16 + (t >> 7)) * 64 + dd) * 128 +
                                  ((t & 127) ^ (vswz(dd) << 3))] = bv8[e];
                }
            }
        }
        return;
    }

    const int mode = blockIdx.z - 1;   // 0:Q 1:K 2:V
    const float* A = (mode == 0) ? Aq : (mode == 1) ? Ak : Av;
    const float* bias = (mode == 0) ? bq : (mode == 1) ? bk : bv;
    const __hip_bfloat16* W = Wb + ((size_t)mode << 20);

    const int tid = threadIdx.x;
    const int w = tid >> 6, lane = tid & 63;
    const int g = lane >> 4, lr = lane & 15;
    const int tm = blockIdx.x * 64, tn = blockIdx.y * 128;
    const int wr = (w >> 1) * 32, wc = (w & 1) * 64;

    floatx4 acc[2][4] = {};

    for (int k0 = 0; k0 < K; k0 += BK) {
        __syncthreads();
#pragma unroll
        for (int it = 0; it < 4; it++) {
            int c0 = it * 256 + w * 64;
            int c = c0 + lane;
            int row = c >> 3, col = (c & 7) * 8;
            gload_lds16(W + (size_t)(tn + row) * K + k0 + col, &Bs[c0 * 8]);
        }
#pragma unroll
        for (int it = 0; it < 2; it++) {
            int c = it * 256 + tid;
            int row = c >> 3, cw = c & 7;
            // swizzled A store (matches swizzled-read pattern below)
            *(short8*)&As[(row * 8 + (cw ^ (row & 7))) * 8] =
                cvt8(A + (size_t)(tm + row) * K + k0 + cw * 8);
        }
        __syncthreads();
#pragma unroll
        for (int kk = 0; kk < 2; kk++) {
            short8 af[2], bf[4];
#pragma unroll
            for (int i = 0; i < 2; i++) {
                int ra = wr + i * 16 + lr;
                af[i] = *(const short8*)&As[ra * BK + (((kk * 4 + g) ^ (ra & 7)) << 3)];
            }
#pragma unroll
            for (int j = 0; j < 4; j++) {
                int rb_ = wc + j * 16 + lr;
                bf[j] = *(const short8*)&Bs[rb_ * BK + (((kk * 4 + g) ^ (rb_ & 7)) << 3)];
            }
#pragma unroll
            for (int i = 0; i < 2; i++)
#pragma unroll
                for (int j = 0; j < 4; j++)
                    acc[i][j] = MFMA16(af[i], bf[j], acc[i][j]);
        }
    }

#pragma unroll
    for (int j = 0; j < 4; j++) {
        int n = tn + wc + j * 16 + lr;
        float bv_ = bias[n];
#pragma unroll
        for (int i = 0; i < 2; i++) {
#pragma unroll
            for (int r = 0; r < 4; r++) {
                int m = tm + wr + i * 16 + g * 4 + r;
                float v = acc[i][j][r] + bv_;
                if (mode == 0) {
                    size_t addr = (size_t)(m >> 10) * ((size_t)Hh * Ll * DHh) +
                                  (size_t)(n >> 6) * ((size_t)Ll * DHh) +
                                  (size_t)(m & 1023) * DHh + (n & 63);
                    qws[addr] = __float2bfloat16(v * (0.125f * LOG2E));
                } else {
                    size_t bh = (size_t)((m >> 10) * Hh + (n >> 6));
                    size_t addr = OUT_ELEMS + (bh * TKV + CL + (m & 1023)) * 128 + (n & 63) +
                                  (mode == 2 ? 64 : 0);
                    outc[addr] = v;
                    int t = CL + (m & 1023);
                    int dd = n & 63;
                    __hip_bfloat16 hv = __float2bfloat16(v);
                    if (mode == 1) {
                        kbf[bh * 131072 + (size_t)t * 64 +
                            (((dd >> 3) ^ (t & 7)) << 3) + (dd & 7)] = hv;
                    } else {
                        vbf[(bh * 16 + (size_t)(t >> 7)) * 8192 + (size_t)dd * 128 +
                            ((t & 127) ^ (vswz(dd) << 3))] = hv;
                    }
                }
            }
        }
    }
}

// ---------------------------------------------------------------------------
// Final projection GEMM (round-16 config): A = bf16 ws (attn out, PRE-SWIZZLED),
// W = swizzled Wb; both staged linear via gload_lds; fragment reads XOR.
// ---------------------------------------------------------------------------
__global__ __launch_bounds__(256) void gemm_out(
    const __hip_bfloat16* __restrict__ A, const __hip_bfloat16* __restrict__ W,
    const float* __restrict__ bias, float* __restrict__ C) {
    constexpr int K = 1024, BK = 64;
    __shared__ alignas(16) __hip_bfloat16 As[64 * BK];
    __shared__ alignas(16) __hip_bfloat16 Bs[128 * BK];

    const int tid = threadIdx.x;
    const int w = tid >> 6, lane = tid & 63;
    const int g = lane >> 4, lr = lane & 15;
    const int tm = blockIdx.x * 64, tn = blockIdx.y * 128;
    const int wr = (w >> 1) * 32, wc = (w & 1) * 64;

    floatx4 acc[2][4] = {};

    for (int k0 = 0; k0 < K; k0 += BK) {
        __syncthreads();
#pragma unroll
        for (int it = 0; it < 4; it++) {
            int c0 = it * 256 + w * 64;
            int c = c0 + lane;
            int row = c >> 3, col = (c & 7) * 8;
            gload_lds16(W + (size_t)(tn + row) * K + k0 + col, &Bs[c0 * 8]);
        }
#pragma unroll
        for (int it = 0; it < 2; it++) {
            int c0 = it * 256 + w * 64;
            int c = c0 + lane;
            int row = c >> 3, col = (c & 7) * 8;
            gload_lds16(A + (size_t)(tm + row) * K + k0 + col, &As[c0 * 8]);
        }
        __syncthreads();
#pragma unroll
        for (int kk = 0; kk < 2; kk++) {
            short8 af[2], bf[4];
#pragma unroll
            for (int i = 0; i < 2; i++) {
                int ra = wr + i * 16 + lr;
                af[i] = *(const short8*)&As[ra * BK + (((kk * 4 + g) ^ (ra & 7)) << 3)];
            }
#pragma unroll
            for (int j = 0; j < 4; j++) {
                int rb_ = wc + j * 16 + lr;
                bf[j] = *(const short8*)&Bs[rb_ * BK + (((kk * 4 + g) ^ (rb_ & 7)) << 3)];
            }
#pragma unroll
            for (int i = 0; i < 2; i++)
#pragma unroll
                for (int j = 0; j < 4; j++)
                    acc[i][j] = MFMA16(af[i], bf[j], acc[i][j]);
        }
    }

#pragma unroll
    for (int j = 0; j < 4; j++) {
        int n = tn + wc + j * 16 + lr;
        float bv = bias[n];
#pragma unroll
        for (int i = 0; i < 2; i++)
#pragma unroll
            for (int r = 0; r < 4; r++) {
                int m = tm + wr + i * 16 + g * 4 + r;
                C[(size_t)m * 1024 + n] = acc[i][j][r] + bv;
            }
    }
}

// ---------------------------------------------------------------------------
// Flash attention: grid (B*H, L/128), 256 threads = 4 waves, wave owns 32 q-rows
// (two 16-row halves sharing every K/V fragment read). KVB=64, Ps stride 72:
// 50.4 KB LDS -> 2 blocks/CU resident (512 blocks) so barrier stalls overlap
// across blocks. K/V via global_load_lds from pre-swizzled side-buffers,
// double-buffered, one barrier per tile. exp2 softmax + defer-max. Output
// PRE-SWIZZLED into aws for gemm_out.
// ---------------------------------------------------------------------------
__global__ __launch_bounds__(256) void attn_kernel(
    const __hip_bfloat16* __restrict__ qws, const __hip_bfloat16* __restrict__ kbf,
    const __hip_bfloat16* __restrict__ vbf, __hip_bfloat16* __restrict__ ows) {
    constexpr int KVB = 64;
    __shared__ alignas(16) __hip_bfloat16 Ks[2][KVB * 64];   // 2 x 8 KB, swizzled
    __shared__ alignas(16) __hip_bfloat16 Vt[2][64 * KVB];   // 2 x 8 KB, swizzled
    __shared__ alignas(16) __hip_bfloat16 Ps[4][32 * 72];    // 36.9 KB

    const int tid = threadIdx.x;
    const int w = tid >> 6, lane = tid & 63;
    const int g = lane >> 4, lr = lane & 15;
    const int bh = blockIdx.x;            // b*16 + h  (x-fastest: L2/XCD locality)
    const int q0 = blockIdx.y * 128 + w * 32;

    const __hip_bfloat16* qbase = qws + (size_t)bh * Ll * DHh;
    const __hip_bfloat16* kb = kbf + (size_t)bh * 131072;
    const __hip_bfloat16* vb = vbf + (size_t)bh * 131072;

    short8 qf[2][2];
#pragma unroll
    for (int i = 0; i < 2; i++)
#pragma unroll
        for (int kk = 0; kk < 2; kk++)
            qf[i][kk] = *(const short8*)
                (qbase + (size_t)(q0 + i * 16 + lr) * DHh + kk * 32 + g * 8);

    // K tile tl: kb + tl*4096, fully linear [64 rows][64 cols swizzled].
    // V tile tl: half of the 128-wide V^T tile (XOR keeps bit6), row stride 128.
#define STAGE(b, tl)                                                          \
    {                                                                         \
        const __hip_bfloat16* kt = kb + (size_t)(tl) * 4096;                  \
        const __hip_bfloat16* vt = vb + (size_t)((tl) >> 1) * 8192 +          \
                                   (size_t)((tl) & 1) * 64;                   \
        _Pragma("unroll")                                                     \
        for (int it = 0; it < 2; it++) {                                      \
            int c = it * 256 + tid;                                           \
            gload_lds16(kt + (size_t)c * 8, &Ks[b][c * 8]);                   \
            gload_lds16(vt + (size_t)(c >> 3) * 128 + (c & 7) * 8,            \
                        &Vt[b][c * 8]);                                       \
        }                                                                     \
    }

    float rm[2][4], rl[2][4];
    floatx4 o[2][4] = {};
#pragma unroll
    for (int i = 0; i < 2; i++)
#pragma unroll
        for (int j = 0; j < 4; j++) { rm[i][j] = -3e38f; rl[i][j] = 0.f; }

    STAGE(0, 0);
    __syncthreads();   // drains vmcnt: tile 0 resident

    int cur = 0;
    for (int tl = 0; tl < 32; ++tl) {
        if (tl < 31) STAGE(cur ^ 1, tl + 1);   // fire next tile; hides under compute

        // S = Q @ K^T: each K fragment read feeds BOTH q-halves (2 MFMAs/read)
        floatx4 s[2][4] = {};
#pragma unroll
        for (int f = 0; f < 4; f++) {
            int row = f * 16 + lr;
#pragma unroll
            for (int kk = 0; kk < 2; kk++) {
                short8 bfr = *(const short8*)
                    &Ks[cur][row * 64 + (((kk * 4 + g) ^ (row & 7)) << 3)];
                s[0][f] = MFMA16(qf[0][kk], bfr, s[0][f]);
                s[1][f] = MFMA16(qf[1][kk], bfr, s[1][f]);
            }
        }

        // online softmax (exp2 domain), defer-max THR=8, per q-half
        bool ok = true;
        float mt[2][4];
#pragma unroll
        for (int i = 0; i < 2; i++)
#pragma unroll
            for (int j = 0; j < 4; j++) {
                float mv = fmaxf(fmaxf(s[i][0][j], s[i][1][j]),
                                 fmaxf(s[i][2][j], s[i][3][j]));
                mv = fmaxf(mv, __shfl_xor(mv, 1));
                mv = fmaxf(mv, __shfl_xor(mv, 2));
                mv = fmaxf(mv, __shfl_xor(mv, 4));
                mv = fmaxf(mv, __shfl_xor(mv, 8));
                mt[i][j] = mv;
                ok = ok && (mv - rm[i][j] <= 8.f);
            }
        if (!__all(ok)) {
#pragma unroll
            for (int i = 0; i < 2; i++)
#pragma unroll
                for (int j = 0; j < 4; j++) {
                    float mn = fmaxf(rm[i][j], mt[i][j]);
                    float corr = fexp2(rm[i][j] - mn);
                    rm[i][j] = mn;
                    rl[i][j] *= corr;
#pragma unroll
                    for (int f2 = 0; f2 < 4; f2++) o[i][f2][j] = o[i][f2][j] * corr;
                }
        }
#pragma unroll
        for (int i = 0; i < 2; i++) {
            float rs[4] = {0.f, 0.f, 0.f, 0.f};
#pragma unroll
            for (int f = 0; f < 4; f++)
#pragma unroll
                for (int j = 0; j < 4; j++) {
                    float p = fexp2(s[i][f][j] - rm[i][j]);
                    s[i][f][j] = p;
                    rs[j] += p;
                }
#pragma unroll
            for (int j = 0; j < 4; j++) {
                rs[j] += __shfl_xor(rs[j], 1);
                rs[j] += __shfl_xor(rs[j], 2);
                rs[j] += __shfl_xor(rs[j], 4);
                rs[j] += __shfl_xor(rs[j], 8);
                rl[i][j] += rs[j];
            }
        }

        // P -> LDS (per-wave region; within-wave dependency only)
        __hip_bfloat16* pw = &Ps[w][0];
#pragma unroll
        for (int i = 0; i < 2; i++)
#pragma unroll
            for (int f = 0; f < 4; f++)
#pragma unroll
                for (int j = 0; j < 4; j++)
                    pw[(i * 16 + g * 4 + j) * 72 + f * 16 + lr] =
                        __float2bfloat16(s[i][f][j]);

        // PV: each V fragment read feeds BOTH q-halves
#pragma unroll
        for (int kk = 0; kk < 2; kk++) {
            short8 pa0 = *(const short8*)&pw[(0 + lr) * 72 + kk * 32 + g * 8];
            short8 pa1 = *(const short8*)&pw[(16 + lr) * 72 + kk * 32 + g * 8];
#pragma unroll
            for (int f2 = 0; f2 < 4; f2++) {
                int d = f2 * 16 + lr;
                short8 vbr = *(const short8*)
                    &Vt[cur][d * KVB + ((kk * 32 + g * 8) ^ (vswz(d) << 3))];
                o[0][f2] = MFMA16(pa0, vbr, o[0][f2]);
                o[1][f2] = MFMA16(pa1, vbr, o[1][f2]);
            }
        }

        __syncthreads();   // single barrier: next tile resident, this buffer free
        cur ^= 1;
    }
#undef STAGE

    // Epilogue: normalize; store bf16 PRE-SWIZZLED into (B,L,D) ws:
    // within the 64-col block h, chunk ch stored at ch ^ (row&7).
    const int b = bh >> 4, h = bh & 15;
#pragma unroll
    for (int i = 0; i < 2; i++)
#pragma unroll
        for (int j = 0; j < 4; j++) {
            float inv = 1.0f / rl[i][j];
            int qrow = q0 + i * 16 + g * 4 + j;
            int sr = qrow & 7;
            size_t rb = ((size_t)b * Ll + qrow) * Dd + (size_t)h * DHh;
#pragma unroll
            for (int f2 = 0; f2 < 4; f2++) {
                int ch = f2 * 2 + (lr >> 3);
                ows[rb + ((ch ^ sr) << 3) + (lr & 7)] =
                    __float2bfloat16(o[i][f2][j] * inv);
            }
        }
}

// ---------------------------------------------------------------------------
extern "C" void kernel_launch(void* const* d_in, const int* in_sizes, int n_in,
                              void* d_out, int out_size, void* d_ws, size_t ws_size,
                              hipStream_t stream) {
    (void)in_sizes; (void)n_in; (void)out_size; (void)ws_size;
    const float* query = (const float*)d_in[0];
    const float* key   = (const float*)d_in[1];
    const float* value = (const float*)d_in[2];
    const float* cache = (const float*)d_in[3];
    const float* Wq = (const float*)d_in[4];
    const float* bq = (const float*)d_in[5];
    const float* Wk = (const float*)d_in[6];
    const float* bk = (const float*)d_in[7];
    const float* Wv = (const float*)d_in[8];
    const float* bv = (const float*)d_in[9];
    const float* Wo = (const float*)d_in[10];
    const float* bo = (const float*)d_in[11];

    float* out = (float*)d_out;
    __hip_bfloat16* qws = (__hip_bfloat16*)d_ws;          // (B,H,L,DH) bf16, 8 MB
    __hip_bfloat16* aws = qws + OUT_ELEMS;                // (B,L,D)    bf16, 8 MB
    __hip_bfloat16* Wb  = aws + OUT_ELEMS;                // 4x 1024^2  bf16, 8 MB
    __hip_bfloat16* kbf = Wb  + OUT_ELEMS;                // swizzled K side, 16 MB
    __hip_bfloat16* vbf = kbf + (8ull << 20);             // swizzled V^T side, 16 MB

    dim3 bb(256);
    convert_w_kernel<<<dim3(2048), bb, 0, stream>>>(Wq, Wk, Wv, Wo, Wb);

    gemm_qkv<<<dim3(64, 8, 4), bb, 0, stream>>>(query, key, value, cache, Wb,
                                                bq, bk, bv, qws, out, kbf, vbf);

    attn_kernel<<<dim3(64, 8), dim3(256), 0, stream>>>(qws, kbf, vbf, aws);

    gemm_out<<<dim3(64, 8), bb, 0, stream>>>(aws, Wb + (3u << 20), bo, out);
}

// Round 19
// 178.234 us; speedup vs baseline: 1.1097x; 1.1097x over previous
//
#include <hip/hip_runtime.h>
#include <hip/hip_bf16.h>
#include <stdint.h>

// Problem constants (f32 I/O; bf16 internal compute)
constexpr int Hh = 16, Ll = 1024, Dd = 1024, DHh = 64, CL = 1024, TKV = 2048;
constexpr size_t OUT_ELEMS = 4ull * 1024 * 1024;   // B*L*D = 4,194,304 floats
constexpr float LOG2E = 1.44269504088896340736f;

typedef __attribute__((ext_vector_type(8))) short short8;
typedef __attribute__((ext_vector_type(4))) float floatx4;

#define MFMA16(a, b, c) __builtin_amdgcn_mfma_f32_16x16x32_bf16(a, b, c, 0, 0, 0)

// native 2^x (v_exp_f32); libm exp2f carries ~6 VALU ops of range handling.
__device__ __forceinline__ float fexp2(float x) {
#if __has_builtin(__builtin_amdgcn_exp2f)
    return __builtin_amdgcn_exp2f(x);
#else
    float r;
    asm("v_exp_f32 %0, %1" : "=v"(r) : "v"(x));
    return r;
#endif
}

__device__ __forceinline__ short bfs(float x) {
    union { __hip_bfloat16 h; short s; } u;
    u.h = __float2bfloat16(x);
    return u.s;
}

__device__ __forceinline__ short8 cvt8(const float* p) {
    float4 a = *(const float4*)p;
    float4 b = *(const float4*)(p + 4);
    short8 r;
    r[0] = bfs(a.x); r[1] = bfs(a.y); r[2] = bfs(a.z); r[3] = bfs(a.w);
    r[4] = bfs(b.x); r[5] = bfs(b.y); r[6] = bfs(b.z); r[7] = bfs(b.w);
    return r;
}

__device__ __forceinline__ void gload_lds16(const __hip_bfloat16* g, __hip_bfloat16* l) {
    __builtin_amdgcn_global_load_lds((const __attribute__((address_space(1))) void*)g,
                                     (__attribute__((address_space(3))) void*)l, 16, 0, 0);
}

// V^T side-buffer swizzle
__device__ __forceinline__ int vswz(int d) { return ((d >> 3) ^ d) & 7; }

// ---------------------------------------------------------------------------
// Convert kernel. Chunks [0, 524288): 4 weight matrices -> swizzled bf16 Wb.
// Chunks [524288, 2097152) (only when grid=8192): query/key/value -> swizzled
// bf16 abf (same per-row chunk-XOR layout, enables linear gload_lds staging).
// ---------------------------------------------------------------------------
__global__ __launch_bounds__(256) void convert_kernel(
    const float* __restrict__ Wq, const float* __restrict__ Wk,
    const float* __restrict__ Wv, const float* __restrict__ Wo,
    const float* __restrict__ query, const float* __restrict__ key,
    const float* __restrict__ value,
    __hip_bfloat16* __restrict__ Wb, __hip_bfloat16* __restrict__ abf) {
    int c = blockIdx.x * 256 + threadIdx.x;
    if (c < 524288) {
        int wsel = c >> 17;
        int within = c & 131071;
        int row = within >> 7;
        int cir = within & 127;
        int kb = cir >> 3, cw = cir & 7;
        const float* src = (wsel == 0) ? Wq : (wsel == 1) ? Wk : (wsel == 2) ? Wv : Wo;
        *(short8*)(Wb + ((size_t)wsel << 20) + ((size_t)row << 10) + (kb << 6) +
                   ((cw ^ (row & 7)) << 3)) = cvt8(src + (size_t)within * 8);
    } else {
        int ci = c - 524288;
        int isel = ci >> 19;                 // 524288 chunks per input
        int within = ci & 524287;
        int row = within >> 7;               // 0..4095
        int cir = within & 127;
        int kb = cir >> 3, cw = cir & 7;
        const float* src = (isel == 0) ? query : (isel == 1) ? key : value;
        *(short8*)(abf + ((size_t)isel << 22) + ((size_t)row << 10) + (kb << 6) +
                   ((cw ^ (row & 7)) << 3)) = cvt8(src + (size_t)within * 8);
    }
}

// ---------------------------------------------------------------------------
// Fused QKV projection GEMM + cache copy: grid (64,8,4).
// z=0: cache copy (memory-bound; dispatched FIRST to overlap GEMM blocks).
// z=1: bf16 Q ws (B,H,L,DH) scaled 0.125*log2e.
// z=2: f32 new_cache K half + bf16 swizzled kbf.
// z=3: f32 new_cache V half + bf16 swizzled vbf.
// ABF=true: A staged via linear gload_lds from pre-swizzled abf (zero VALU).
// ABF=false: A staged f32 -> cvt8 -> swizzled ds_write (round-16 fallback).
// LDS tiles chunk-swizzled (T2): fragment reads XOR chunk with row&7 -> 0 conf.
// ---------------------------------------------------------------------------
template <bool ABF>
__global__ __launch_bounds__(256) void gemm_qkv(
    const float* __restrict__ Aq, const float* __restrict__ Ak,
    const float* __restrict__ Av, const __hip_bfloat16* __restrict__ abf,
    const float* __restrict__ cache, const __hip_bfloat16* __restrict__ Wb,
    const float* __restrict__ bq, const float* __restrict__ bk,
    const float* __restrict__ bv, __hip_bfloat16* __restrict__ qws,
    float* __restrict__ outc, __hip_bfloat16* __restrict__ kbf,
    __hip_bfloat16* __restrict__ vbf) {
    constexpr int K = 1024, BK = 64;
    __shared__ alignas(16) __hip_bfloat16 As[64 * BK];    //  8 KB
    __shared__ alignas(16) __hip_bfloat16 Bs[128 * BK];   // 16 KB

    if (blockIdx.z == 0) {
        // ---- cache copy slice: 512 blocks x 2048 chunks of 8 floats ----
        int id = blockIdx.y * 64 + blockIdx.x;
#pragma unroll
        for (int it = 0; it < 8; it++) {
            int c = id * 2048 + it * 256 + threadIdx.x;   // [0, 1048576)
            int bh  = c >> 14;
            int rem = c & 16383;
            int t = rem >> 4, part = rem & 15;            // 0-7: K, 8-15: V
            const float* s = cache + (size_t)c * 8;
            float* d = outc + OUT_ELEMS + (size_t)bh * 262144 + (size_t)rem * 8;
            *(float4*)d       = *(const float4*)s;
            *(float4*)(d + 4) = *(const float4*)(s + 4);
            short8 bv8 = cvt8(s);
            if (part < 8) {
                *(short8*)&kbf[(size_t)bh * 131072 + (size_t)t * 64 +
                               ((part ^ (t & 7)) << 3)] = bv8;
            } else {
                int d0 = (part - 8) * 8;
#pragma unroll
                for (int e = 0; e < 8; e++) {
                    int dd = d0 + e;
                    ((short*)vbf)[((size_t)(bh * 16 + (t >> 7)) * 64 + dd) * 128 +
                                  ((t & 127) ^ (vswz(dd) << 3))] = bv8[e];
                }
            }
        }
        return;
    }

    const int mode = blockIdx.z - 1;   // 0:Q 1:K 2:V
    const float* A = (mode == 0) ? Aq : (mode == 1) ? Ak : Av;
    const __hip_bfloat16* Ab = abf + ((size_t)mode << 22);
    const float* bias = (mode == 0) ? bq : (mode == 1) ? bk : bv;
    const __hip_bfloat16* W = Wb + ((size_t)mode << 20);

    const int tid = threadIdx.x;
    const int w = tid >> 6, lane = tid & 63;
    const int g = lane >> 4, lr = lane & 15;
    const int tm = blockIdx.x * 64, tn = blockIdx.y * 128;
    const int wr = (w >> 1) * 32, wc = (w & 1) * 64;

    floatx4 acc[2][4] = {};

    for (int k0 = 0; k0 < K; k0 += BK) {
        __syncthreads();
#pragma unroll
        for (int it = 0; it < 4; it++) {
            int c0 = it * 256 + w * 64;
            int c = c0 + lane;
            int row = c >> 3, col = (c & 7) * 8;
            gload_lds16(W + (size_t)(tn + row) * K + k0 + col, &Bs[c0 * 8]);
        }
        if (ABF) {
#pragma unroll
            for (int it = 0; it < 2; it++) {
                int c0 = it * 256 + w * 64;
                int c = c0 + lane;
                int row = c >> 3, col = (c & 7) * 8;
                gload_lds16(Ab + (size_t)(tm + row) * K + k0 + col, &As[c0 * 8]);
            }
        } else {
#pragma unroll
            for (int it = 0; it < 2; it++) {
                int c = it * 256 + tid;
                int row = c >> 3, cw = c & 7;
                *(short8*)&As[(row * 8 + (cw ^ (row & 7))) * 8] =
                    cvt8(A + (size_t)(tm + row) * K + k0 + cw * 8);
            }
        }
        __syncthreads();
#pragma unroll
        for (int kk = 0; kk < 2; kk++) {
            short8 af[2], bf[4];
#pragma unroll
            for (int i = 0; i < 2; i++) {
                int ra = wr + i * 16 + lr;
                af[i] = *(const short8*)&As[ra * BK + (((kk * 4 + g) ^ (ra & 7)) << 3)];
            }
#pragma unroll
            for (int j = 0; j < 4; j++) {
                int rb_ = wc + j * 16 + lr;
                bf[j] = *(const short8*)&Bs[rb_ * BK + (((kk * 4 + g) ^ (rb_ & 7)) << 3)];
            }
#pragma unroll
            for (int i = 0; i < 2; i++)
#pragma unroll
                for (int j = 0; j < 4; j++)
                    acc[i][j] = MFMA16(af[i], bf[j], acc[i][j]);
        }
    }

#pragma unroll
    for (int j = 0; j < 4; j++) {
        int n = tn + wc + j * 16 + lr;
        float bv_ = bias[n];
#pragma unroll
        for (int i = 0; i < 2; i++) {
#pragma unroll
            for (int r = 0; r < 4; r++) {
                int m = tm + wr + i * 16 + g * 4 + r;
                float v = acc[i][j][r] + bv_;
                if (mode == 0) {
                    size_t addr = (size_t)(m >> 10) * ((size_t)Hh * Ll * DHh) +
                                  (size_t)(n >> 6) * ((size_t)Ll * DHh) +
                                  (size_t)(m & 1023) * DHh + (n & 63);
                    qws[addr] = __float2bfloat16(v * (0.125f * LOG2E));
                } else {
                    size_t bh = (size_t)((m >> 10) * Hh + (n >> 6));
                    size_t addr = OUT_ELEMS + (bh * TKV + CL + (m & 1023)) * 128 + (n & 63) +
                                  (mode == 2 ? 64 : 0);
                    outc[addr] = v;
                    int t = CL + (m & 1023);
                    int dd = n & 63;
                    __hip_bfloat16 hv = __float2bfloat16(v);
                    if (mode == 1) {
                        kbf[bh * 131072 + (size_t)t * 64 +
                            (((dd >> 3) ^ (t & 7)) << 3) + (dd & 7)] = hv;
                    } else {
                        vbf[(bh * 16 + (size_t)(t >> 7)) * 8192 + (size_t)dd * 128 +
                            ((t & 127) ^ (vswz(dd) << 3))] = hv;
                    }
                }
            }
        }
    }
}

// ---------------------------------------------------------------------------
// Final projection GEMM: A = bf16 ws (attn out, PRE-SWIZZLED), W = swizzled Wb;
// both staged linear via gload_lds; fragment reads XOR.
// ---------------------------------------------------------------------------
__global__ __launch_bounds__(256) void gemm_out(
    const __hip_bfloat16* __restrict__ A, const __hip_bfloat16* __restrict__ W,
    const float* __restrict__ bias, float* __restrict__ C) {
    constexpr int K = 1024, BK = 64;
    __shared__ alignas(16) __hip_bfloat16 As[64 * BK];
    __shared__ alignas(16) __hip_bfloat16 Bs[128 * BK];

    const int tid = threadIdx.x;
    const int w = tid >> 6, lane = tid & 63;
    const int g = lane >> 4, lr = lane & 15;
    const int tm = blockIdx.x * 64, tn = blockIdx.y * 128;
    const int wr = (w >> 1) * 32, wc = (w & 1) * 64;

    floatx4 acc[2][4] = {};

    for (int k0 = 0; k0 < K; k0 += BK) {
        __syncthreads();
#pragma unroll
        for (int it = 0; it < 4; it++) {
            int c0 = it * 256 + w * 64;
            int c = c0 + lane;
            int row = c >> 3, col = (c & 7) * 8;
            gload_lds16(W + (size_t)(tn + row) * K + k0 + col, &Bs[c0 * 8]);
        }
#pragma unroll
        for (int it = 0; it < 2; it++) {
            int c0 = it * 256 + w * 64;
            int c = c0 + lane;
            int row = c >> 3, col = (c & 7) * 8;
            gload_lds16(A + (size_t)(tm + row) * K + k0 + col, &As[c0 * 8]);
        }
        __syncthreads();
#pragma unroll
        for (int kk = 0; kk < 2; kk++) {
            short8 af[2], bf[4];
#pragma unroll
            for (int i = 0; i < 2; i++) {
                int ra = wr + i * 16 + lr;
                af[i] = *(const short8*)&As[ra * BK + (((kk * 4 + g) ^ (ra & 7)) << 3)];
            }
#pragma unroll
            for (int j = 0; j < 4; j++) {
                int rb_ = wc + j * 16 + lr;
                bf[j] = *(const short8*)&Bs[rb_ * BK + (((kk * 4 + g) ^ (rb_ & 7)) << 3)];
            }
#pragma unroll
            for (int i = 0; i < 2; i++)
#pragma unroll
                for (int j = 0; j < 4; j++)
                    acc[i][j] = MFMA16(af[i], bf[j], acc[i][j]);
        }
    }

#pragma unroll
    for (int j = 0; j < 4; j++) {
        int n = tn + wc + j * 16 + lr;
        float bv = bias[n];
#pragma unroll
        for (int i = 0; i < 2; i++)
#pragma unroll
            for (int r = 0; r < 4; r++) {
                int m = tm + wr + i * 16 + g * 4 + r;
                C[(size_t)m * 1024 + n] = acc[i][j][r] + bv;
            }
    }
}

// ---------------------------------------------------------------------------
// Flash attention (round-16 benched config): grid (B*H, L/256), 512 threads =
// 8 waves, wave owns 32 q-rows (two 16-row halves sharing every K/V fragment
// read). KVB=128; K/V via global_load_lds from pre-swizzled side-buffers,
// double-buffered, one barrier per tile. exp2 softmax + defer-max. Output
// PRE-SWIZZLED into aws for gemm_out.
// ---------------------------------------------------------------------------
__global__ __launch_bounds__(512) void attn_kernel(
    const __hip_bfloat16* __restrict__ qws, const __hip_bfloat16* __restrict__ kbf,
    const __hip_bfloat16* __restrict__ vbf, __hip_bfloat16* __restrict__ ows) {
    constexpr int KVB = 128;
    __shared__ alignas(16) __hip_bfloat16 Ks[2][KVB * 64];   // 2 x 16 KB, swizzled
    __shared__ alignas(16) __hip_bfloat16 Vt[2][64 * KVB];   // 2 x 16 KB, swizzled
    __shared__ alignas(16) __hip_bfloat16 Ps[8][32 * 136];   // 69.6 KB

    const int tid = threadIdx.x;
    const int w = tid >> 6, lane = tid & 63;
    const int g = lane >> 4, lr = lane & 15;
    const int bh = blockIdx.x;            // b*16 + h  (x-fastest: L2/XCD locality)
    const int q0 = blockIdx.y * 256 + w * 32;

    const __hip_bfloat16* qbase = qws + (size_t)bh * Ll * DHh;
    const __hip_bfloat16* kb = kbf + (size_t)bh * 131072;  // 16 tiles x 8192 elems
    const __hip_bfloat16* vb = vbf + (size_t)bh * 131072;

    short8 qf[2][2];
#pragma unroll
    for (int i = 0; i < 2; i++)
#pragma unroll
        for (int kk = 0; kk < 2; kk++)
            qf[i][kk] = *(const short8*)
                (qbase + (size_t)(q0 + i * 16 + lr) * DHh + kk * 32 + g * 8);

#define STAGE(b, tl)                                                          \
    {                                                                         \
        const __hip_bfloat16* kt = kb + (size_t)(tl) * 8192;                  \
        const __hip_bfloat16* vt = vb + (size_t)(tl) * 8192;                  \
        _Pragma("unroll")                                                     \
        for (int it = 0; it < 2; it++) {                                      \
            int c0 = it * 512 + w * 64;                                       \
            gload_lds16(kt + (size_t)(c0 + lane) * 8, &Ks[b][c0 * 8]);        \
            gload_lds16(vt + (size_t)(c0 + lane) * 8, &Vt[b][c0 * 8]);        \
        }                                                                     \
    }

    float rm[2][4], rl[2][4];
    floatx4 o[2][4] = {};
#pragma unroll
    for (int i = 0; i < 2; i++)
#pragma unroll
        for (int j = 0; j < 4; j++) { rm[i][j] = -3e38f; rl[i][j] = 0.f; }

    STAGE(0, 0);
    __syncthreads();   // drains vmcnt: tile 0 resident

    int cur = 0;
    for (int tl = 0; tl < 16; ++tl) {
        if (tl < 15) STAGE(cur ^ 1, tl + 1);   // fire next tile; hides under compute

        // S = Q @ K^T: each K fragment read feeds BOTH q-halves (2 MFMAs/read)
        floatx4 s[2][8] = {};
#pragma unroll
        for (int f = 0; f < 8; f++) {
            int row = f * 16 + lr;
#pragma unroll
            for (int kk = 0; kk < 2; kk++) {
                short8 bfr = *(const short8*)
                    &Ks[cur][row * 64 + (((kk * 4 + g) ^ (row & 7)) << 3)];
                s[0][f] = MFMA16(qf[0][kk], bfr, s[0][f]);
                s[1][f] = MFMA16(qf[1][kk], bfr, s[1][f]);
            }
        }

        // online softmax (exp2 domain), defer-max THR=8, per q-half
        bool ok = true;
        float mt[2][4];
#pragma unroll
        for (int i = 0; i < 2; i++)
#pragma unroll
            for (int j = 0; j < 4; j++) {
                float mv = fmaxf(
                    fmaxf(fmaxf(s[i][0][j], s[i][1][j]), fmaxf(s[i][2][j], s[i][3][j])),
                    fmaxf(fmaxf(s[i][4][j], s[i][5][j]), fmaxf(s[i][6][j], s[i][7][j])));
                mv = fmaxf(mv, __shfl_xor(mv, 1));
                mv = fmaxf(mv, __shfl_xor(mv, 2));
                mv = fmaxf(mv, __shfl_xor(mv, 4));
                mv = fmaxf(mv, __shfl_xor(mv, 8));
                mt[i][j] = mv;
                ok = ok && (mv - rm[i][j] <= 8.f);
            }
        if (!__all(ok)) {
#pragma unroll
            for (int i = 0; i < 2; i++)
#pragma unroll
                for (int j = 0; j < 4; j++) {
                    float mn = fmaxf(rm[i][j], mt[i][j]);
                    float corr = fexp2(rm[i][j] - mn);
                    rm[i][j] = mn;
                    rl[i][j] *= corr;
#pragma unroll
                    for (int f2 = 0; f2 < 4; f2++) o[i][f2][j] = o[i][f2][j] * corr;
                }
        }
#pragma unroll
        for (int i = 0; i < 2; i++) {
            float rs[4] = {0.f, 0.f, 0.f, 0.f};
#pragma unroll
            for (int f = 0; f < 8; f++)
#pragma unroll
                for (int j = 0; j < 4; j++) {
                    float p = fexp2(s[i][f][j] - rm[i][j]);
                    s[i][f][j] = p;
                    rs[j] += p;
                }
#pragma unroll
            for (int j = 0; j < 4; j++) {
                rs[j] += __shfl_xor(rs[j], 1);
                rs[j] += __shfl_xor(rs[j], 2);
                rs[j] += __shfl_xor(rs[j], 4);
                rs[j] += __shfl_xor(rs[j], 8);
                rl[i][j] += rs[j];
            }
        }

        // P -> LDS (per-wave region; within-wave dependency only)
        __hip_bfloat16* pw = &Ps[w][0];
#pragma unroll
        for (int i = 0; i < 2; i++)
#pragma unroll
            for (int f = 0; f < 8; f++)
#pragma unroll
                for (int j = 0; j < 4; j++)
                    pw[(i * 16 + g * 4 + j) * 136 + f * 16 + lr] =
                        __float2bfloat16(s[i][f][j]);

        // PV: each V fragment read feeds BOTH q-halves
#pragma unroll
        for (int kk = 0; kk < 4; kk++) {
            short8 pa0 = *(const short8*)&pw[(0 + lr) * 136 + kk * 32 + g * 8];
            short8 pa1 = *(const short8*)&pw[(16 + lr) * 136 + kk * 32 + g * 8];
#pragma unroll
            for (int f2 = 0; f2 < 4; f2++) {
                int d = f2 * 16 + lr;
                short8 vbr = *(const short8*)
                    &Vt[cur][d * KVB + ((kk * 32 + g * 8) ^ (vswz(d) << 3))];
                o[0][f2] = MFMA16(pa0, vbr, o[0][f2]);
                o[1][f2] = MFMA16(pa1, vbr, o[1][f2]);
            }
        }

        __syncthreads();   // single barrier: next tile resident, this buffer free
        cur ^= 1;
    }
#undef STAGE

    // Epilogue: normalize; store bf16 PRE-SWIZZLED into (B,L,D) ws:
    // within the 64-col block h, chunk ch stored at ch ^ (row&7).
    const int b = bh >> 4, h = bh & 15;
#pragma unroll
    for (int i = 0; i < 2; i++)
#pragma unroll
        for (int j = 0; j < 4; j++) {
            float inv = 1.0f / rl[i][j];
            int qrow = q0 + i * 16 + g * 4 + j;
            int sr = qrow & 7;
            size_t rb = ((size_t)b * Ll + qrow) * Dd + (size_t)h * DHh;
#pragma unroll
            for (int f2 = 0; f2 < 4; f2++) {
                int ch = f2 * 2 + (lr >> 3);
                ows[rb + ((ch ^ sr) << 3) + (lr & 7)] =
                    __float2bfloat16(o[i][f2][j] * inv);
            }
        }
}

// ---------------------------------------------------------------------------
extern "C" void kernel_launch(void* const* d_in, const int* in_sizes, int n_in,
                              void* d_out, int out_size, void* d_ws, size_t ws_size,
                              hipStream_t stream) {
    (void)in_sizes; (void)n_in; (void)out_size;
    const float* query = (const float*)d_in[0];
    const float* key   = (const float*)d_in[1];
    const float* value = (const float*)d_in[2];
    const float* cache = (const float*)d_in[3];
    const float* Wq = (const float*)d_in[4];
    const float* bq = (const float*)d_in[5];
    const float* Wk = (const float*)d_in[6];
    const float* bk = (const float*)d_in[7];
    const float* Wv = (const float*)d_in[8];
    const float* bv = (const float*)d_in[9];
    const float* Wo = (const float*)d_in[10];
    const float* bo = (const float*)d_in[11];

    float* out = (float*)d_out;
    __hip_bfloat16* qws = (__hip_bfloat16*)d_ws;          // 4M bf16 (8 MB)
    __hip_bfloat16* aws = qws + OUT_ELEMS;                // 4M
    __hip_bfloat16* Wb  = aws + OUT_ELEMS;                // 4M
    __hip_bfloat16* kbf = Wb  + OUT_ELEMS;                // 8M
    __hip_bfloat16* vbf = kbf + (8ull << 20);             // 8M
    __hip_bfloat16* abf = vbf + (8ull << 20);             // 12M (QKV swizzled bf16)

    const bool use_abf = ws_size >= 40ull * 1024 * 1024 * 2;  // 80 MB

    dim3 bb(256);
    convert_kernel<<<dim3(use_abf ? 8192 : 2048), bb, 0, stream>>>(
        Wq, Wk, Wv, Wo, query, key, value, Wb, abf);

    if (use_abf)
        gemm_qkv<true><<<dim3(64, 8, 4), bb, 0, stream>>>(
            query, key, value, abf, cache, Wb, bq, bk, bv, qws, out, kbf, vbf);
    else
        gemm_qkv<false><<<dim3(64, 8, 4), bb, 0, stream>>>(
            query, key, value, abf, cache, Wb, bq, bk, bv, qws, out, kbf, vbf);

    attn_kernel<<<dim3(64, 4), dim3(512), 0, stream>>>(qws, kbf, vbf, aws);

    gemm_out<<<dim3(64, 8), bb, 0, stream>>>(aws, Wb + (3u << 20), bo, out);
}

// Round 20
// 166.731 us; speedup vs baseline: 1.1863x; 1.0690x over previous
//
#include <hip/hip_runtime.h>
#include <hip/hip_bf16.h>
#include <stdint.h>

// Problem constants (f32 I/O; bf16 internal compute)
constexpr int Hh = 16, Ll = 1024, Dd = 1024, DHh = 64, CL = 1024, TKV = 2048;
constexpr size_t OUT_ELEMS = 4ull * 1024 * 1024;   // B*L*D = 4,194,304 floats
constexpr float LOG2E = 1.44269504088896340736f;

typedef __attribute__((ext_vector_type(8))) short short8;
typedef __attribute__((ext_vector_type(4))) float floatx4;

#define MFMA16(a, b, c) __builtin_amdgcn_mfma_f32_16x16x32_bf16(a, b, c, 0, 0, 0)

// native 2^x (v_exp_f32); libm exp2f carries ~6 VALU ops of range handling.
__device__ __forceinline__ float fexp2(float x) {
#if __has_builtin(__builtin_amdgcn_exp2f)
    return __builtin_amdgcn_exp2f(x);
#else
    float r;
    asm("v_exp_f32 %0, %1" : "=v"(r) : "v"(x));
    return r;
#endif
}

__device__ __forceinline__ short bfs(float x) {
    union { __hip_bfloat16 h; short s; } u;
    u.h = __float2bfloat16(x);
    return u.s;
}

__device__ __forceinline__ short8 cvt8(const float* p) {
    float4 a = *(const float4*)p;
    float4 b = *(const float4*)(p + 4);
    short8 r;
    r[0] = bfs(a.x); r[1] = bfs(a.y); r[2] = bfs(a.z); r[3] = bfs(a.w);
    r[4] = bfs(b.x); r[5] = bfs(b.y); r[6] = bfs(b.z); r[7] = bfs(b.w);
    return r;
}

__device__ __forceinline__ void gload_lds16(const __hip_bfloat16* g, __hip_bfloat16* l) {
    __builtin_amdgcn_global_load_lds((const __attribute__((address_space(1))) void*)g,
                                     (__attribute__((address_space(3))) void*)l, 16, 0, 0);
}

// V^T side-buffer swizzle: element (t,d) -> vbf[((bh*16 + t/128)*64 + d)*128 + ((t&127) ^ (sw(d)<<3))]
__device__ __forceinline__ int vswz(int d) { return ((d >> 3) ^ d) & 7; }

// ---------------------------------------------------------------------------
// Prep: 4 weight matrices (1024x1024 f32) -> bf16 ws, CHUNK-SWIZZLED layout:
// within each row's 64-col block, 8-elem chunk cw stored at cw ^ (row&7).
// Linear global_load_lds then lands a swizzled LDS image; fragment reads XOR.
// ---------------------------------------------------------------------------
__global__ __launch_bounds__(256) void convert_w_kernel(
    const float* __restrict__ Wq, const float* __restrict__ Wk,
    const float* __restrict__ Wv, const float* __restrict__ Wo,
    __hip_bfloat16* __restrict__ Wb) {
    int c = blockIdx.x * 256 + threadIdx.x;   // 524,288 chunks of 8
    int wsel = c >> 17;
    int within = c & 131071;                  // chunk within matrix
    int row = within >> 7;                    // 128 chunks per row
    int cir = within & 127;                   // chunk in row
    int kb = cir >> 3, cw = cir & 7;
    int swc = cw ^ (row & 7);
    const float* src = (wsel == 0) ? Wq : (wsel == 1) ? Wk : (wsel == 2) ? Wv : Wo;
    *(short8*)(Wb + ((size_t)wsel << 20) + ((size_t)row << 10) + (kb << 6) + (swc << 3)) =
        cvt8(src + (size_t)within * 8);
}

// ---------------------------------------------------------------------------
// Fused QKV projection GEMM + cache copy: grid (64,8,4).
// z=0: cache copy (memory-bound; dispatched FIRST so it overlaps GEMM blocks).
// z=1: bf16 Q ws (B,H,L,DH) scaled 0.125*log2e.
// z=2: f32 new_cache K half + bf16 swizzled kbf.
// z=3: f32 new_cache V half + bf16 swizzled vbf.
// LDS tiles chunk-swizzled (T2): reads XOR chunk with row&7 -> 0 conflicts.
// ---------------------------------------------------------------------------
__global__ __launch_bounds__(256) void gemm_qkv(
    const float* __restrict__ Aq, const float* __restrict__ Ak,
    const float* __restrict__ Av, const float* __restrict__ cache,
    const __hip_bfloat16* __restrict__ Wb,
    const float* __restrict__ bq, const float* __restrict__ bk,
    const float* __restrict__ bv, __hip_bfloat16* __restrict__ qws,
    float* __restrict__ outc, __hip_bfloat16* __restrict__ kbf,
    __hip_bfloat16* __restrict__ vbf) {
    constexpr int K = 1024, BK = 64;
    __shared__ alignas(16) __hip_bfloat16 As[64 * BK];    //  8 KB
    __shared__ alignas(16) __hip_bfloat16 Bs[128 * BK];   // 16 KB

    if (blockIdx.z == 0) {
        // ---- cache copy slice: 512 blocks x 2048 chunks of 8 floats ----
        int id = blockIdx.y * 64 + blockIdx.x;
#pragma unroll
        for (int it = 0; it < 8; it++) {
            int c = id * 2048 + it * 256 + threadIdx.x;   // [0, 1048576)
            int bh  = c >> 14;
            int rem = c & 16383;
            int t = rem >> 4, part = rem & 15;            // 0-7: K, 8-15: V
            const float* s = cache + (size_t)c * 8;
            float* d = outc + OUT_ELEMS + (size_t)bh * 262144 + (size_t)rem * 8;
            *(float4*)d       = *(const float4*)s;
            *(float4*)(d + 4) = *(const float4*)(s + 4);
            short8 bv8 = cvt8(s);
            if (part < 8) {
                *(short8*)&kbf[(size_t)bh * 131072 + (size_t)t * 64 +
                               ((part ^ (t & 7)) << 3)] = bv8;
            } else {
                int d0 = (part - 8) * 8;
#pragma unroll
                for (int e = 0; e < 8; e++) {
                    int dd = d0 + e;
                    ((short*)vbf)[((size_t)(bh * 16 + (t >> 7)) * 64 + dd) * 128 +
                                  ((t & 127) ^ (vswz(dd) << 3))] = bv8[e];
                }
            }
        }
        return;
    }

    const int mode = blockIdx.z - 1;   // 0:Q 1:K 2:V
    const float* A = (mode == 0) ? Aq : (mode == 1) ? Ak : Av;
    const float* bias = (mode == 0) ? bq : (mode == 1) ? bk : bv;
    const __hip_bfloat16* W = Wb + ((size_t)mode << 20);

    const int tid = threadIdx.x;
    const int w = tid >> 6, lane = tid & 63;
    const int g = lane >> 4, lr = lane & 15;
    const int tm = blockIdx.x * 64, tn = blockIdx.y * 128;
    const int wr = (w >> 1) * 32, wc = (w & 1) * 64;

    floatx4 acc[2][4] = {};

    for (int k0 = 0; k0 < K; k0 += BK) {
        __syncthreads();
#pragma unroll
        for (int it = 0; it < 4; it++) {
            int c0 = it * 256 + w * 64;
            int c = c0 + lane;
            int row = c >> 3, col = (c & 7) * 8;
            gload_lds16(W + (size_t)(tn + row) * K + k0 + col, &Bs[c0 * 8]);
        }
#pragma unroll
        for (int it = 0; it < 2; it++) {
            int c = it * 256 + tid;
            int row = c >> 3, cw = c & 7;
            // swizzled A store (matches swizzled-read pattern below)
            *(short8*)&As[(row * 8 + (cw ^ (row & 7))) * 8] =
                cvt8(A + (size_t)(tm + row) * K + k0 + cw * 8);
        }
        __syncthreads();
#pragma unroll
        for (int kk = 0; kk < 2; kk++) {
            short8 af[2], bf[4];
#pragma unroll
            for (int i = 0; i < 2; i++) {
                int ra = wr + i * 16 + lr;
                af[i] = *(const short8*)&As[ra * BK + (((kk * 4 + g) ^ (ra & 7)) << 3)];
            }
#pragma unroll
            for (int j = 0; j < 4; j++) {
                int rb_ = wc + j * 16 + lr;
                bf[j] = *(const short8*)&Bs[rb_ * BK + (((kk * 4 + g) ^ (rb_ & 7)) << 3)];
            }
#pragma unroll
            for (int i = 0; i < 2; i++)
#pragma unroll
                for (int j = 0; j < 4; j++)
                    acc[i][j] = MFMA16(af[i], bf[j], acc[i][j]);
        }
    }

#pragma unroll
    for (int j = 0; j < 4; j++) {
        int n = tn + wc + j * 16 + lr;
        float bv_ = bias[n];
#pragma unroll
        for (int i = 0; i < 2; i++) {
#pragma unroll
            for (int r = 0; r < 4; r++) {
                int m = tm + wr + i * 16 + g * 4 + r;
                float v = acc[i][j][r] + bv_;
                if (mode == 0) {
                    size_t addr = (size_t)(m >> 10) * ((size_t)Hh * Ll * DHh) +
                                  (size_t)(n >> 6) * ((size_t)Ll * DHh) +
                                  (size_t)(m & 1023) * DHh + (n & 63);
                    qws[addr] = __float2bfloat16(v * (0.125f * LOG2E));
                } else {
                    size_t bh = (size_t)((m >> 10) * Hh + (n >> 6));
                    size_t addr = OUT_ELEMS + (bh * TKV + CL + (m & 1023)) * 128 + (n & 63) +
                                  (mode == 2 ? 64 : 0);
                    outc[addr] = v;
                    int t = CL + (m & 1023);
                    int dd = n & 63;
                    __hip_bfloat16 hv = __float2bfloat16(v);
                    if (mode == 1) {
                        kbf[bh * 131072 + (size_t)t * 64 +
                            (((dd >> 3) ^ (t & 7)) << 3) + (dd & 7)] = hv;
                    } else {
                        vbf[(bh * 16 + (size_t)(t >> 7)) * 8192 + (size_t)dd * 128 +
                            ((t & 127) ^ (vswz(dd) << 3))] = hv;
                    }
                }
            }
        }
    }
}

// ---------------------------------------------------------------------------
// Final projection GEMM: A = bf16 ws (attn out, PRE-SWIZZLED), W = swizzled Wb;
// both staged linear via gload_lds; fragment reads XOR the chunk.
// ---------------------------------------------------------------------------
__global__ __launch_bounds__(256) void gemm_out(
    const __hip_bfloat16* __restrict__ A, const __hip_bfloat16* __restrict__ W,
    const float* __restrict__ bias, float* __restrict__ C) {
    constexpr int K = 1024, BK = 64;
    __shared__ alignas(16) __hip_bfloat16 As[64 * BK];
    __shared__ alignas(16) __hip_bfloat16 Bs[128 * BK];

    const int tid = threadIdx.x;
    const int w = tid >> 6, lane = tid & 63;
    const int g = lane >> 4, lr = lane & 15;
    const int tm = blockIdx.x * 64, tn = blockIdx.y * 128;
    const int wr = (w >> 1) * 32, wc = (w & 1) * 64;

    floatx4 acc[2][4] = {};

    for (int k0 = 0; k0 < K; k0 += BK) {
        __syncthreads();
#pragma unroll
        for (int it = 0; it < 4; it++) {
            int c0 = it * 256 + w * 64;
            int c = c0 + lane;
            int row = c >> 3, col = (c & 7) * 8;
            gload_lds16(W + (size_t)(tn + row) * K + k0 + col, &Bs[c0 * 8]);
        }
#pragma unroll
        for (int it = 0; it < 2; it++) {
            int c0 = it * 256 + w * 64;
            int c = c0 + lane;
            int row = c >> 3, col = (c & 7) * 8;
            gload_lds16(A + (size_t)(tm + row) * K + k0 + col, &As[c0 * 8]);
        }
        __syncthreads();
#pragma unroll
        for (int kk = 0; kk < 2; kk++) {
            short8 af[2], bf[4];
#pragma unroll
            for (int i = 0; i < 2; i++) {
                int ra = wr + i * 16 + lr;
                af[i] = *(const short8*)&As[ra * BK + (((kk * 4 + g) ^ (ra & 7)) << 3)];
            }
#pragma unroll
            for (int j = 0; j < 4; j++) {
                int rb_ = wc + j * 16 + lr;
                bf[j] = *(const short8*)&Bs[rb_ * BK + (((kk * 4 + g) ^ (rb_ & 7)) << 3)];
            }
#pragma unroll
            for (int i = 0; i < 2; i++)
#pragma unroll
                for (int j = 0; j < 4; j++)
                    acc[i][j] = MFMA16(af[i], bf[j], acc[i][j]);
        }
    }

#pragma unroll
    for (int j = 0; j < 4; j++) {
        int n = tn + wc + j * 16 + lr;
        float bv = bias[n];
#pragma unroll
        for (int i = 0; i < 2; i++)
#pragma unroll
            for (int r = 0; r < 4; r++) {
                int m = tm + wr + i * 16 + g * 4 + r;
                C[(size_t)m * 1024 + n] = acc[i][j][r] + bv;
            }
    }
}

// ---------------------------------------------------------------------------
// Flash attention: grid (B*H, L/256), 512 threads = 8 waves, wave owns 32 q-rows
// (two 16-row fragment sets sharing every K/V fragment read). K/V staged via
// global_load_lds from pre-swizzled bf16 side-buffers, double-buffered, one
// barrier per tile. exp2-domain softmax + defer-max. Output written into aws
// PRE-SWIZZLED (chunk ^ row&7 within 64-col blocks) for gemm_out's A staging.
// ---------------------------------------------------------------------------
__global__ __launch_bounds__(512) void attn_kernel(
    const __hip_bfloat16* __restrict__ qws, const __hip_bfloat16* __restrict__ kbf,
    const __hip_bfloat16* __restrict__ vbf, __hip_bfloat16* __restrict__ ows) {
    constexpr int KVB = 128;
    __shared__ alignas(16) __hip_bfloat16 Ks[2][KVB * 64];   // 2 x 16 KB, swizzled
    __shared__ alignas(16) __hip_bfloat16 Vt[2][64 * KVB];   // 2 x 16 KB, swizzled
    __shared__ alignas(16) __hip_bfloat16 Ps[8][32 * 136];   // 69.6 KB

    const int tid = threadIdx.x;
    const int w = tid >> 6, lane = tid & 63;
    const int g = lane >> 4, lr = lane & 15;
    const int bh = blockIdx.x;            // b*16 + h  (x-fastest: L2/XCD locality)
    const int q0 = blockIdx.y * 256 + w * 32;

    const __hip_bfloat16* qbase = qws + (size_t)bh * Ll * DHh;
    const __hip_bfloat16* kb = kbf + (size_t)bh * 131072;  // 16 tiles x 8192 elems
    const __hip_bfloat16* vb = vbf + (size_t)bh * 131072;

    short8 qf[2][2];
#pragma unroll
    for (int i = 0; i < 2; i++)
#pragma unroll
        for (int kk = 0; kk < 2; kk++)
            qf[i][kk] = *(const short8*)
                (qbase + (size_t)(q0 + i * 16 + lr) * DHh + kk * 32 + g * 8);

#define STAGE(b, tl)                                                          \
    {                                                                         \
        const __hip_bfloat16* kt = kb + (size_t)(tl) * 8192;                  \
        const __hip_bfloat16* vt = vb + (size_t)(tl) * 8192;                  \
        _Pragma("unroll")                                                     \
        for (int it = 0; it < 2; it++) {                                      \
            int c0 = it * 512 + w * 64;                                       \
            gload_lds16(kt + (size_t)(c0 + lane) * 8, &Ks[b][c0 * 8]);        \
            gload_lds16(vt + (size_t)(c0 + lane) * 8, &Vt[b][c0 * 8]);        \
        }                                                                     \
    }

    float rm[2][4], rl[2][4];
    floatx4 o[2][4] = {};
#pragma unroll
    for (int i = 0; i < 2; i++)
#pragma unroll
        for (int j = 0; j < 4; j++) { rm[i][j] = -3e38f; rl[i][j] = 0.f; }

    STAGE(0, 0);
    __syncthreads();   // drains vmcnt: tile 0 resident

    int cur = 0;
    for (int tl = 0; tl < 16; ++tl) {
        if (tl < 15) STAGE(cur ^ 1, tl + 1);   // fire next tile; hides under compute

        // S = Q @ K^T: each K fragment read feeds BOTH q-halves (2 MFMAs/read)
        floatx4 s[2][8] = {};
#pragma unroll
        for (int f = 0; f < 8; f++) {
            int row = f * 16 + lr;
#pragma unroll
            for (int kk = 0; kk < 2; kk++) {
                short8 bfr = *(const short8*)
                    &Ks[cur][row * 64 + (((kk * 4 + g) ^ (row & 7)) << 3)];
                s[0][f] = MFMA16(qf[0][kk], bfr, s[0][f]);
                s[1][f] = MFMA16(qf[1][kk], bfr, s[1][f]);
            }
        }

        // online softmax (exp2 domain), defer-max THR=8, per q-half
        bool ok = true;
        float mt[2][4];
#pragma unroll
        for (int i = 0; i < 2; i++)
#pragma unroll
            for (int j = 0; j < 4; j++) {
                float mv = fmaxf(
                    fmaxf(fmaxf(s[i][0][j], s[i][1][j]), fmaxf(s[i][2][j], s[i][3][j])),
                    fmaxf(fmaxf(s[i][4][j], s[i][5][j]), fmaxf(s[i][6][j], s[i][7][j])));
                mv = fmaxf(mv, __shfl_xor(mv, 1));
                mv = fmaxf(mv, __shfl_xor(mv, 2));
                mv = fmaxf(mv, __shfl_xor(mv, 4));
                mv = fmaxf(mv, __shfl_xor(mv, 8));
                mt[i][j] = mv;
                ok = ok && (mv - rm[i][j] <= 8.f);
            }
        if (!__all(ok)) {
#pragma unroll
            for (int i = 0; i < 2; i++)
#pragma unroll
                for (int j = 0; j < 4; j++) {
                    float mn = fmaxf(rm[i][j], mt[i][j]);
                    float corr = fexp2(rm[i][j] - mn);
                    rm[i][j] = mn;
                    rl[i][j] *= corr;
#pragma unroll
                    for (int f2 = 0; f2 < 4; f2++) o[i][f2][j] = o[i][f2][j] * corr;
                }
        }
#pragma unroll
        for (int i = 0; i < 2; i++) {
            float rs[4] = {0.f, 0.f, 0.f, 0.f};
#pragma unroll
            for (int f = 0; f < 8; f++)
#pragma unroll
                for (int j = 0; j < 4; j++) {
                    float p = fexp2(s[i][f][j] - rm[i][j]);
                    s[i][f][j] = p;
                    rs[j] += p;
                }
#pragma unroll
            for (int j = 0; j < 4; j++) {
                rs[j] += __shfl_xor(rs[j], 1);
                rs[j] += __shfl_xor(rs[j], 2);
                rs[j] += __shfl_xor(rs[j], 4);
                rs[j] += __shfl_xor(rs[j], 8);
                rl[i][j] += rs[j];
            }
        }

        // P -> LDS (per-wave region; within-wave dependency only)
        __hip_bfloat16* pw = &Ps[w][0];
#pragma unroll
        for (int i = 0; i < 2; i++)
#pragma unroll
            for (int f = 0; f < 8; f++)
#pragma unroll
                for (int j = 0; j < 4; j++)
                    pw[(i * 16 + g * 4 + j) * 136 + f * 16 + lr] =
                        __float2bfloat16(s[i][f][j]);

        // PV: each V fragment read feeds BOTH q-halves
#pragma unroll
        for (int kk = 0; kk < 4; kk++) {
            short8 pa0 = *(const short8*)&pw[(0 + lr) * 136 + kk * 32 + g * 8];
            short8 pa1 = *(const short8*)&pw[(16 + lr) * 136 + kk * 32 + g * 8];
#pragma unroll
            for (int f2 = 0; f2 < 4; f2++) {
                int d = f2 * 16 + lr;
                short8 vbr = *(const short8*)
                    &Vt[cur][d * KVB + ((kk * 32 + g * 8) ^ (vswz(d) << 3))];
                o[0][f2] = MFMA16(pa0, vbr, o[0][f2]);
                o[1][f2] = MFMA16(pa1, vbr, o[1][f2]);
            }
        }

        __syncthreads();   // single barrier: next tile resident, this buffer free
        cur ^= 1;
    }
#undef STAGE

    // Epilogue: normalize; store bf16 PRE-SWIZZLED into (B,L,D) ws:
    // within the 64-col block h, chunk ch stored at ch ^ (row&7).
    const int b = bh >> 4, h = bh & 15;
#pragma unroll
    for (int i = 0; i < 2; i++)
#pragma unroll
        for (int j = 0; j < 4; j++) {
            float inv = 1.0f / rl[i][j];
            int qrow = q0 + i * 16 + g * 4 + j;
            int sr = qrow & 7;
            size_t rb = ((size_t)b * Ll + qrow) * Dd + (size_t)h * DHh;
#pragma unroll
            for (int f2 = 0; f2 < 4; f2++) {
                int ch = f2 * 2 + (lr >> 3);
                ows[rb + ((ch ^ sr) << 3) + (lr & 7)] =
                    __float2bfloat16(o[i][f2][j] * inv);
            }
        }
}

// ---------------------------------------------------------------------------
extern "C" void kernel_launch(void* const* d_in, const int* in_sizes, int n_in,
                              void* d_out, int out_size, void* d_ws, size_t ws_size,
                              hipStream_t stream) {
    (void)in_sizes; (void)n_in; (void)out_size; (void)ws_size;
    const float* query = (const float*)d_in[0];
    const float* key   = (const float*)d_in[1];
    const float* value = (const float*)d_in[2];
    const float* cache = (const float*)d_in[3];
    const float* Wq = (const float*)d_in[4];
    const float* bq = (const float*)d_in[5];
    const float* Wk = (const float*)d_in[6];
    const float* bk = (const float*)d_in[7];
    const float* Wv = (const float*)d_in[8];
    const float* bv = (const float*)d_in[9];
    const float* Wo = (const float*)d_in[10];
    const float* bo = (const float*)d_in[11];

    float* out = (float*)d_out;
    __hip_bfloat16* qws = (__hip_bfloat16*)d_ws;          // (B,H,L,DH) bf16, 8 MB
    __hip_bfloat16* aws = qws + OUT_ELEMS;                // (B,L,D)    bf16, 8 MB
    __hip_bfloat16* Wb  = aws + OUT_ELEMS;                // 4x 1024^2  bf16, 8 MB
    __hip_bfloat16* kbf = Wb  + OUT_ELEMS;                // swizzled K side, 16 MB
    __hip_bfloat16* vbf = kbf + (8ull << 20);             // swizzled V^T side, 16 MB

    dim3 bb(256);
    convert_w_kernel<<<dim3(2048), bb, 0, stream>>>(Wq, Wk, Wv, Wo, Wb);

    gemm_qkv<<<dim3(64, 8, 4), bb, 0, stream>>>(query, key, value, cache, Wb,
                                                bq, bk, bv, qws, out, kbf, vbf);

    attn_kernel<<<dim3(64, 4), dim3(512), 0, stream>>>(qws, kbf, vbf, aws);

    gemm_out<<<dim3(64, 8), bb, 0, stream>>>(aws, Wb + (3u << 20), bo, out);
}